// Round 1
// baseline (402.829 us; speedup 1.0000x reference)
//
#include <hip/hip_runtime.h>
#include <hip/hip_bf16.h>
#include <math.h>

#define Bn 8
#define Ln 512
#define Dn 768
#define NHn 12
#define DHn 64
#define K1n 20
#define K2n 20

// workspace layout (bytes)
#define WS_ACC    0          // double acc[8]: [0]=num_pair [1]=num_trip [2]=sum_smask
#define WS_GSCORE 64         // float g_score[8*512]
#define WS_LOC    16448      // float loc_pre[8*512*512] (8 MB)
#define WS_GTOP   8405056    // int g_top[8*20]
#define WS_LTOP   8405696    // int l_top[8*20*20]
#define WS_ZERO_BYTES 8405056

#define PITCH_A 68
#define PITCH_B 132
#define PITCH_T 516

// ---------------------------------------------------------------------------
// Kernel 1: per (b,h,i-tile of 32): masked scores for s and t, sum (s-t)^2,
// t softmax -> att, atomic accumulate loc_pre[b,i,j] (sum over h) and
// g_score[b,j] (sum over h,i).
// ---------------------------------------------------------------------------
__global__ __launch_bounds__(256, 1) void pair_main_kernel(
    const float* __restrict__ s_rep, const float* __restrict__ t_rep,
    const float* __restrict__ mask, float* __restrict__ loc_pre,
    float* __restrict__ g_score, double* __restrict__ acc) {
  const int b = blockIdx.z, h = blockIdx.y, it = blockIdx.x;
  const int i0 = it * 32;
  const int tid = threadIdx.x;

  __shared__ float As[32][PITCH_A], At[32][PITCH_A];
  __shared__ float Bs[64][PITCH_B], Bt[64][PITCH_B];   // transposed: [kk][j]
  __shared__ float Ts[32][PITCH_T];
  __shared__ float Mcol[Ln];
  __shared__ float Mrow[32];
  __shared__ float RowScale[32];
  __shared__ float wred[4];

  // stage A tiles (32 rows x 64 dims of head h)
  for (int idx = tid; idx < 32 * 16; idx += 256) {
    int r = idx >> 4, c4 = idx & 15;
    size_t goff = ((size_t)(b * Ln + i0 + r)) * Dn + h * DHn + c4 * 4;
    float4 va = *(const float4*)(s_rep + goff);
    float4 vb = *(const float4*)(t_rep + goff);
    *(float4*)&As[r][c4 * 4] = va;
    *(float4*)&At[r][c4 * 4] = vb;
  }
  for (int j = tid; j < Ln; j += 256) Mcol[j] = mask[b * Ln + j];
  if (tid < 32) Mrow[tid] = mask[b * Ln + i0 + tid];
  __syncthreads();

  const int ig = tid >> 5, jg = tid & 31;
  const int ib = ig * 4, jb = jg * 4;
  float lpair = 0.0f;

  for (int jt = 0; jt < 4; ++jt) {
    const int j0 = jt * 128;
    // stage B tiles transposed into [kk][j]
    for (int idx = tid; idx < 128 * 16; idx += 256) {
      int r = idx >> 4, c4 = idx & 15;
      size_t goff = ((size_t)(b * Ln + j0 + r)) * Dn + h * DHn + c4 * 4;
      float4 vs = *(const float4*)(s_rep + goff);
      float4 vt = *(const float4*)(t_rep + goff);
      int kk = c4 * 4;
      Bs[kk + 0][r] = vs.x; Bs[kk + 1][r] = vs.y; Bs[kk + 2][r] = vs.z; Bs[kk + 3][r] = vs.w;
      Bt[kk + 0][r] = vt.x; Bt[kk + 1][r] = vt.y; Bt[kk + 2][r] = vt.z; Bt[kk + 3][r] = vt.w;
    }
    __syncthreads();

    float accs[4][4] = {{0}}, acct[4][4] = {{0}};
    for (int kk = 0; kk < DHn; kk += 4) {
      float a_sv[4][4], a_tv[4][4];
      #pragma unroll
      for (int ii = 0; ii < 4; ++ii) {
        float4 ta = *(const float4*)&As[ib + ii][kk];
        float4 tb = *(const float4*)&At[ib + ii][kk];
        a_sv[ii][0] = ta.x; a_sv[ii][1] = ta.y; a_sv[ii][2] = ta.z; a_sv[ii][3] = ta.w;
        a_tv[ii][0] = tb.x; a_tv[ii][1] = tb.y; a_tv[ii][2] = tb.z; a_tv[ii][3] = tb.w;
      }
      #pragma unroll
      for (int q = 0; q < 4; ++q) {
        float4 bs4 = *(const float4*)&Bs[kk + q][jb];
        float4 bt4 = *(const float4*)&Bt[kk + q][jb];
        #pragma unroll
        for (int ii = 0; ii < 4; ++ii) {
          float avs = a_sv[ii][q], avt = a_tv[ii][q];
          accs[ii][0] += avs * bs4.x; accs[ii][1] += avs * bs4.y;
          accs[ii][2] += avs * bs4.z; accs[ii][3] += avs * bs4.w;
          acct[ii][0] += avt * bt4.x; acct[ii][1] += avt * bt4.y;
          acct[ii][2] += avt * bt4.z; acct[ii][3] += avt * bt4.w;
        }
      }
    }
    // epilogue: masked scores, diff^2, stash t softmax input
    #pragma unroll
    for (int ii = 0; ii < 4; ++ii) {
      int il = ib + ii;
      float mi = Mrow[il];
      float z[4];
      #pragma unroll
      for (int jj = 0; jj < 4; ++jj) {
        int j = j0 + jb + jj;
        float mm = mi * Mcol[j];
        float ss = accs[ii][jj] * 0.125f * mm;
        float st = acct[ii][jj] * 0.125f * mm;
        float dd = ss - st;
        lpair += dd * dd;
        z[jj] = st + (1.0f - mm) * (-10000.0f);
      }
      *(float4*)&Ts[il][j0 + jb] = make_float4(z[0], z[1], z[2], z[3]);
    }
    __syncthreads();
  }

  // softmax per row (8 threads per row)
  {
    int r = tid >> 3, sub = tid & 7;
    float m = -3.0e38f;
    for (int j = sub; j < Ln; j += 8) m = fmaxf(m, Ts[r][j]);
    #pragma unroll
    for (int o = 1; o < 8; o <<= 1) m = fmaxf(m, __shfl_xor(m, o, 64));
    float ssum = 0.0f;
    for (int j = sub; j < Ln; j += 8) {
      float e = __expf(Ts[r][j] - m);
      Ts[r][j] = e;
      ssum += e;
    }
    #pragma unroll
    for (int o = 1; o < 8; o <<= 1) ssum += __shfl_xor(ssum, o, 64);
    if (sub == 0) RowScale[r] = Mrow[r] / ssum;
  }
  __syncthreads();

  // accumulate att into loc_pre (atomic over h) and g_score (atomic over h,i)
  {
    int j0 = tid, j1 = tid + 256;
    float mj0 = Mcol[j0], mj1 = Mcol[j1];
    float g0 = 0.0f, g1 = 0.0f;
    size_t base = ((size_t)(b * Ln + i0)) * Ln;
    for (int r = 0; r < 32; ++r) {
      float sc = RowScale[r];
      float v0 = Ts[r][j0] * sc * mj0;
      float v1 = Ts[r][j1] * sc * mj1;
      atomicAdd(&loc_pre[base + (size_t)r * Ln + j0], v0);
      atomicAdd(&loc_pre[base + (size_t)r * Ln + j1], v1);
      g0 += v0; g1 += v1;
    }
    atomicAdd(&g_score[b * Ln + j0], g0);
    atomicAdd(&g_score[b * Ln + j1], g1);
  }

  // reduce pair-loss partial
  #pragma unroll
  for (int o = 1; o < 64; o <<= 1) lpair += __shfl_xor(lpair, o, 64);
  if ((tid & 63) == 0) wred[tid >> 6] = lpair;
  __syncthreads();
  if (tid == 0)
    atomicAdd(&acc[0], (double)((wred[0] + wred[1]) + (wred[2] + wred[3])));
}

// ---------------------------------------------------------------------------
// Top-k helpers: iterative argmax with tie -> lowest index (jax.lax.top_k).
// ---------------------------------------------------------------------------
__global__ void topk_g_kernel(const float* __restrict__ g_score, int* __restrict__ g_top) {
  int b = blockIdx.x, tid = threadIdx.x;
  __shared__ float vals[Ln];
  __shared__ float bv[256];
  __shared__ int bi[256];
  vals[tid] = g_score[b * Ln + tid];
  vals[tid + 256] = g_score[b * Ln + tid + 256];
  __syncthreads();
  for (int r = 0; r < K1n; ++r) {
    float v0 = vals[tid], v1 = vals[tid + 256];
    float v; int idx;
    if (v1 > v0) { v = v1; idx = tid + 256; } else { v = v0; idx = tid; }
    bv[tid] = v; bi[tid] = idx;
    __syncthreads();
    for (int s = 128; s > 0; s >>= 1) {
      if (tid < s) {
        float ov = bv[tid + s]; int oi = bi[tid + s];
        if (ov > bv[tid] || (ov == bv[tid] && oi < bi[tid])) { bv[tid] = ov; bi[tid] = oi; }
      }
      __syncthreads();
    }
    if (tid == 0) { g_top[b * K1n + r] = bi[0]; vals[bi[0]] = -3.0e38f; }
    __syncthreads();
  }
}

__global__ void topk_l_kernel(const float* __restrict__ loc_pre,
                              const int* __restrict__ g_top, int* __restrict__ l_top) {
  int blk = blockIdx.x, tid = threadIdx.x;
  int b = blk / K1n, i1 = blk % K1n;
  int g = g_top[b * K1n + i1];
  __shared__ float vals[Ln];
  __shared__ float bv[256];
  __shared__ int bi[256];
  size_t rb = ((size_t)(b * Ln + g)) * Ln;
  vals[tid] = loc_pre[rb + tid];
  vals[tid + 256] = loc_pre[rb + tid + 256];
  __syncthreads();
  if (tid == 0) vals[g] = 0.0f;   // (1 - eye) zeroing of diagonal
  __syncthreads();
  for (int r = 0; r < K2n; ++r) {
    float v0 = vals[tid], v1 = vals[tid + 256];
    float v; int idx;
    if (v1 > v0) { v = v1; idx = tid + 256; } else { v = v0; idx = tid; }
    bv[tid] = v; bi[tid] = idx;
    __syncthreads();
    for (int s = 128; s > 0; s >>= 1) {
      if (tid < s) {
        float ov = bv[tid + s]; int oi = bi[tid + s];
        if (ov > bv[tid] || (ov == bv[tid] && oi < bi[tid])) { bv[tid] = ov; bi[tid] = oi; }
      }
      __syncthreads();
    }
    if (tid == 0) { l_top[(b * K1n + i1) * K2n + r] = bi[0]; vals[bi[0]] = -3.0e38f; }
    __syncthreads();
  }
}

// ---------------------------------------------------------------------------
// Kernel: triplet loss. One block per (b, i1). Normalized difference vectors
// for s and t in LDS, Gram via wave-per-pair (j<k symmetry -> x2).
// ---------------------------------------------------------------------------
__global__ __launch_bounds__(256, 1) void triplet_kernel(
    const float* __restrict__ s_rep, const float* __restrict__ t_rep,
    const float* __restrict__ mask, const int* __restrict__ g_top,
    const int* __restrict__ l_top, double* __restrict__ acc) {
  int blk = blockIdx.x, tid = threadIdx.x;
  int b = blk / K1n, i1 = blk % K1n;
  int wid = tid >> 6, lane = tid & 63;
  __shared__ float NS[K2n][Dn];
  __shared__ float NT[K2n][Dn];
  __shared__ int lidx[K2n];
  __shared__ float fl2[K2n];
  __shared__ float sred[4], cred[4];

  int g = g_top[b * K1n + i1];
  if (tid < K2n) {
    int li = l_top[(b * K1n + i1) * K2n + tid];
    lidx[tid] = li;
    fl2[tid] = (mask[b * Ln + g] + mask[b * Ln + li] == 2.0f) ? 1.0f : 0.0f;
  }
  __syncthreads();

  const float* pgs = s_rep + ((size_t)(b * Ln + g)) * Dn;
  const float* pgt = t_rep + ((size_t)(b * Ln + g)) * Dn;
  for (int j = wid; j < K2n; j += 4) {
    const float* pls = s_rep + ((size_t)(b * Ln + lidx[j])) * Dn;
    const float* plt = t_rep + ((size_t)(b * Ln + lidx[j])) * Dn;
    float4 ds[3], dt[3];
    float ssq = 0.0f, tsq = 0.0f;
    #pragma unroll
    for (int q = 0; q < 3; ++q) {
      int c = lane * 4 + q * 256;
      float4 a = *(const float4*)&pgs[c];
      float4 x = *(const float4*)&pls[c];
      ds[q] = make_float4(a.x - x.x, a.y - x.y, a.z - x.z, a.w - x.w);
      ssq += ds[q].x * ds[q].x + ds[q].y * ds[q].y + ds[q].z * ds[q].z + ds[q].w * ds[q].w;
      float4 c2 = *(const float4*)&pgt[c];
      float4 y = *(const float4*)&plt[c];
      dt[q] = make_float4(c2.x - y.x, c2.y - y.y, c2.z - y.z, c2.w - y.w);
      tsq += dt[q].x * dt[q].x + dt[q].y * dt[q].y + dt[q].z * dt[q].z + dt[q].w * dt[q].w;
    }
    #pragma unroll
    for (int o = 1; o < 64; o <<= 1) {
      ssq += __shfl_xor(ssq, o, 64);
      tsq += __shfl_xor(tsq, o, 64);
    }
    float sinv = 1.0f / fmaxf(sqrtf(ssq), 1e-12f);
    float tinv = 1.0f / fmaxf(sqrtf(tsq), 1e-12f);
    #pragma unroll
    for (int q = 0; q < 3; ++q) {
      int c = lane * 4 + q * 256;
      *(float4*)&NS[j][c] = make_float4(ds[q].x * sinv, ds[q].y * sinv, ds[q].z * sinv, ds[q].w * sinv);
      *(float4*)&NT[j][c] = make_float4(dt[q].x * tinv, dt[q].y * tinv, dt[q].z * tinv, dt[q].w * tinv);
    }
  }
  __syncthreads();

  float psum = 0.0f, pcnt = 0.0f;
  for (int p = wid; p < (K2n * (K2n - 1)) / 2; p += 4) {
    int j = 0, base = 0;
    while (p >= base + (K2n - 1 - j)) { base += K2n - 1 - j; ++j; }
    int k = j + 1 + (p - base);
    float dots = 0.0f, dott = 0.0f;
    #pragma unroll
    for (int q = 0; q < 3; ++q) {
      int c = lane * 4 + q * 256;
      float4 xs = *(const float4*)&NS[j][c];
      float4 ys = *(const float4*)&NS[k][c];
      dots += xs.x * ys.x + xs.y * ys.y + xs.z * ys.z + xs.w * ys.w;
      float4 xt = *(const float4*)&NT[j][c];
      float4 yt = *(const float4*)&NT[k][c];
      dott += xt.x * yt.x + xt.y * yt.y + xt.z * yt.z + xt.w * yt.w;
    }
    #pragma unroll
    for (int o = 1; o < 64; o <<= 1) {
      dots += __shfl_xor(dots, o, 64);
      dott += __shfl_xor(dott, o, 64);
    }
    if (lane == 0) {
      float am = fl2[j] * fl2[k];
      bool smv = (am != 0.0f) && (dots != 0.0f);
      bool tmv = (am != 0.0f) && (dott != 0.0f);
      float sv = smv ? dots : 0.0f;
      float tv = tmv ? dott : 0.0f;
      float d = sv - tv;
      float ad = fabsf(d);
      float sl1 = (ad < 1.0f) ? 0.5f * d * d : (ad - 0.5f);
      psum += 2.0f * sl1;                 // symmetric (j,k)/(k,j)
      pcnt += smv ? 2.0f : 0.0f;
    }
  }
  if (lane == 0) { sred[wid] = psum; cred[wid] = pcnt; }
  __syncthreads();
  if (tid == 0) {
    atomicAdd(&acc[1], (double)(sred[0] + sred[1] + sred[2] + sred[3]));
    atomicAdd(&acc[2], (double)(cred[0] + cred[1] + cred[2] + cred[3]));
  }
}

// ---------------------------------------------------------------------------
// Finalize: sum(mext) = sum_b (sum_i m)^2; combine losses.
// ---------------------------------------------------------------------------
__global__ void finalize_kernel(const float* __restrict__ mask,
                                const double* __restrict__ acc, float* __restrict__ out) {
  int tid = threadIdx.x;
  __shared__ float red[4];
  double sm = 0.0;
  for (int b = 0; b < Bn; ++b) {
    float p = 0.0f;
    for (int i = tid; i < Ln; i += 256) p += mask[b * Ln + i];
    #pragma unroll
    for (int o = 1; o < 64; o <<= 1) p += __shfl_xor(p, o, 64);
    __syncthreads();
    if ((tid & 63) == 0) red[tid >> 6] = p;
    __syncthreads();
    if (tid == 0) {
      float rs = red[0] + red[1] + red[2] + red[3];
      sm += (double)rs * (double)rs;
    }
  }
  __syncthreads();
  if (tid == 0) {
    double lp = acc[0] / ((double)NHn * sm);
    double lt = acc[1] / acc[2];
    out[0] = (float)(lp + lt);
  }
}

// ---------------------------------------------------------------------------
extern "C" void kernel_launch(void* const* d_in, const int* in_sizes, int n_in,
                              void* d_out, int out_size, void* d_ws, size_t ws_size,
                              hipStream_t stream) {
  const float* s_rep = (const float*)d_in[0];
  const float* t_rep = (const float*)d_in[1];
  const float* mask  = (const float*)d_in[2];
  float* out = (float*)d_out;

  char* w = (char*)d_ws;
  double* acc     = (double*)(w + WS_ACC);
  float* g_score  = (float*)(w + WS_GSCORE);
  float* loc_pre  = (float*)(w + WS_LOC);
  int* g_top      = (int*)(w + WS_GTOP);
  int* l_top      = (int*)(w + WS_LTOP);

  hipMemsetAsync(d_ws, 0, WS_ZERO_BYTES, stream);

  pair_main_kernel<<<dim3(Ln / 32, NHn, Bn), 256, 0, stream>>>(
      s_rep, t_rep, mask, loc_pre, g_score, acc);
  topk_g_kernel<<<Bn, 256, 0, stream>>>(g_score, g_top);
  topk_l_kernel<<<Bn * K1n, 256, 0, stream>>>(loc_pre, g_top, l_top);
  triplet_kernel<<<Bn * K1n, 256, 0, stream>>>(s_rep, t_rep, mask, g_top, l_top, acc);
  finalize_kernel<<<1, 256, 0, stream>>>(mask, acc, out);
}

// Round 2
// 192.669 us; speedup vs baseline: 2.0908x; 2.0908x over previous
//
#include <hip/hip_runtime.h>
#include <hip/hip_bf16.h>
#include <math.h>

#define Bn 8
#define Ln 512
#define Dn 768
#define NHn 12
#define DHn 64
#define K1n 20
#define K2n 20

// workspace layout (bytes)
#define WS_ACC    0          // double acc[8]: [0]=num_pair [1]=num_trip [2]=sum_smask
#define WS_GSCORE 64         // float g_score[8*512]
#define WS_LOC    16448      // float loc_pre[8*512*512] (8 MB)
#define WS_GTOP   8405056    // int g_top[8*20]
#define WS_LTOP   8405696    // int l_top[8*20*20]  (ends 8418496)
#define WS_SBF    8418496    // ushort sbf[8*12*512*64] head-major bf16 (6.29 MB)
#define WS_TBF    14709952   // ushort tbf[...]       (ends 21001408)
#define WS_ZERO_BYTES 16448  // only acc + g_score need zeroing now

typedef __attribute__((ext_vector_type(8))) short bf16x8;
typedef __attribute__((ext_vector_type(4))) float f32x4;

__device__ inline unsigned short f2bf(float x) {
  __hip_bfloat16 h = __float2bfloat16(x);
  return *reinterpret_cast<unsigned short*>(&h);
}

// ---------------------------------------------------------------------------
// Prep: fp32 [b][row][h*64+k] -> bf16 head-major [b][h][row][k]
// ---------------------------------------------------------------------------
__global__ __launch_bounds__(256) void prep_bf16_kernel(
    const float* __restrict__ s, const float* __restrict__ t,
    unsigned short* __restrict__ sbf, unsigned short* __restrict__ tbf) {
  int gid = blockIdx.x * 256 + threadIdx.x;     // 786432 threads, 4 floats each
  int f = gid * 4;
  int col = f % Dn;
  int rb = f / Dn;
  int row = rb & (Ln - 1);
  int b = rb >> 9;
  int h = col >> 6;
  int k = col & 63;
  size_t dst = (((size_t)(b * NHn + h) * Ln + row) * DHn + k);
  float4 vs = *(const float4*)(s + f);
  float4 vt = *(const float4*)(t + f);
  ushort4 us, ut;
  us.x = f2bf(vs.x); us.y = f2bf(vs.y); us.z = f2bf(vs.z); us.w = f2bf(vs.w);
  ut.x = f2bf(vt.x); ut.y = f2bf(vt.y); ut.z = f2bf(vt.z); ut.w = f2bf(vt.w);
  *(ushort4*)(sbf + dst) = us;
  *(ushort4*)(tbf + dst) = ut;
}

// ---------------------------------------------------------------------------
// Pair kernel v2: one block per (b, 16-row i-tile). All 12 heads fused.
// MFMA bf16 scores for s and t, diff^2, per-head t-softmax, accumulate
// att over heads into LDS loc_acc, single non-atomic loc_pre write.
// ---------------------------------------------------------------------------
#define PITCH_L 516

__global__ __launch_bounds__(256, 1) void pair2_kernel(
    const unsigned short* __restrict__ sbf, const unsigned short* __restrict__ tbf,
    const float* __restrict__ mask, float* __restrict__ loc_pre,
    float* __restrict__ g_score, double* __restrict__ acc) {
  const int b = blockIdx.x & 7;
  const int it = blockIdx.x >> 3;
  const int i0 = it * 16;
  const int tid = threadIdx.x;
  const int w = tid >> 6;        // wave 0..3, cols [w*128, w*128+128)
  const int lane = tid & 63;
  const int lr = lane & 15;      // frag row-sel / C col-sel
  const int lg = lane >> 4;      // 0..3

  __shared__ float loc_acc[16][PITCH_L];
  __shared__ float Mcol[Ln];
  __shared__ float Mrow[16];
  __shared__ float redmax[4][16];
  __shared__ float redsum[4][16];
  __shared__ float wred[4];

  for (int idx = tid; idx < 16 * PITCH_L; idx += 256)
    (&loc_acc[0][0])[idx] = 0.0f;
  for (int j = tid; j < Ln; j += 256) Mcol[j] = mask[b * Ln + j];
  if (tid < 16) Mrow[tid] = mask[b * Ln + i0 + tid];
  __syncthreads();

  const int j_base = w * 128;
  const f32x4 zero4 = {0.0f, 0.0f, 0.0f, 0.0f};
  float lpair = 0.0f;

  for (int h = 0; h < NHn; ++h) {
    const size_t hb = (size_t)(b * NHn + h) * Ln;
    // A fragments: rows i0+lr, k = lg*8 (+32 for kstep1)
    const unsigned short* pas = sbf + (hb + i0 + lr) * DHn + lg * 8;
    const unsigned short* pat = tbf + (hb + i0 + lr) * DHn + lg * 8;
    bf16x8 sa0 = *(const bf16x8*)(pas);
    bf16x8 sa1 = *(const bf16x8*)(pas + 32);
    bf16x8 ta0 = *(const bf16x8*)(pat);
    bf16x8 ta1 = *(const bf16x8*)(pat + 32);

    f32x4 sacc[8], tacc[8];
    #pragma unroll
    for (int ct = 0; ct < 8; ++ct) {
      const int j0 = j_base + ct * 16;
      const unsigned short* pbs = sbf + (hb + j0 + lr) * DHn + lg * 8;
      const unsigned short* pbt = tbf + (hb + j0 + lr) * DHn + lg * 8;
      bf16x8 sb0 = *(const bf16x8*)(pbs);
      bf16x8 sb1 = *(const bf16x8*)(pbs + 32);
      bf16x8 tb0 = *(const bf16x8*)(pbt);
      bf16x8 tb1 = *(const bf16x8*)(pbt + 32);
      f32x4 a0 = __builtin_amdgcn_mfma_f32_16x16x32_bf16(sa0, sb0, zero4, 0, 0, 0);
      sacc[ct]  = __builtin_amdgcn_mfma_f32_16x16x32_bf16(sa1, sb1, a0, 0, 0, 0);
      f32x4 a1 = __builtin_amdgcn_mfma_f32_16x16x32_bf16(ta0, tb0, zero4, 0, 0, 0);
      tacc[ct]  = __builtin_amdgcn_mfma_f32_16x16x32_bf16(ta1, tb1, a1, 0, 0, 0);
    }

    // epilogue: masked diff^2 into lpair; overwrite tacc with z = masked t + bias
    float rmax[4] = {-3.0e38f, -3.0e38f, -3.0e38f, -3.0e38f};
    #pragma unroll
    for (int ct = 0; ct < 8; ++ct) {
      const int j = j_base + ct * 16 + lr;
      const float mj = Mcol[j];
      #pragma unroll
      for (int q = 0; q < 4; ++q) {
        const int r = lg * 4 + q;
        const float mm = Mrow[r] * mj;
        const float ss = sacc[ct][q] * 0.125f * mm;
        const float st = tacc[ct][q] * 0.125f * mm;
        const float d = ss - st;
        lpair += d * d;
        const float z = st + (1.0f - mm) * (-10000.0f);
        tacc[ct][q] = z;
        rmax[q] = fmaxf(rmax[q], z);
      }
    }
    // row max over the wave's 128 cols (reduce across 16 lanes sharing lg)
    #pragma unroll
    for (int o = 1; o < 16; o <<= 1) {
      #pragma unroll
      for (int q = 0; q < 4; ++q) rmax[q] = fmaxf(rmax[q], __shfl_xor(rmax[q], o, 64));
    }
    if (lr == 0) {
      #pragma unroll
      for (int q = 0; q < 4; ++q) redmax[w][lg * 4 + q] = rmax[q];
    }
    __syncthreads();
    float fm[4], rsum[4];
    #pragma unroll
    for (int q = 0; q < 4; ++q) {
      const int r = lg * 4 + q;
      fm[q] = fmaxf(fmaxf(redmax[0][r], redmax[1][r]), fmaxf(redmax[2][r], redmax[3][r]));
      rsum[q] = 0.0f;
    }
    #pragma unroll
    for (int ct = 0; ct < 8; ++ct) {
      #pragma unroll
      for (int q = 0; q < 4; ++q) {
        const float e = __expf(tacc[ct][q] - fm[q]);
        tacc[ct][q] = e;
        rsum[q] += e;
      }
    }
    #pragma unroll
    for (int o = 1; o < 16; o <<= 1) {
      #pragma unroll
      for (int q = 0; q < 4; ++q) rsum[q] += __shfl_xor(rsum[q], o, 64);
    }
    if (lr == 0) {
      #pragma unroll
      for (int q = 0; q < 4; ++q) redsum[w][lg * 4 + q] = rsum[q];
    }
    __syncthreads();
    float rscale[4];
    #pragma unroll
    for (int q = 0; q < 4; ++q) {
      const int r = lg * 4 + q;
      const float fs = redsum[0][r] + redsum[1][r] + redsum[2][r] + redsum[3][r];
      rscale[q] = Mrow[r] / fs;
    }
    #pragma unroll
    for (int ct = 0; ct < 8; ++ct) {
      const int j = j_base + ct * 16 + lr;
      const float mj = Mcol[j];
      #pragma unroll
      for (int q = 0; q < 4; ++q) {
        const int r = lg * 4 + q;
        loc_acc[r][j] += tacc[ct][q] * rscale[q] * mj;
      }
    }
    __syncthreads();
  }

  // pair-loss partial -> acc[0]
  #pragma unroll
  for (int o = 1; o < 64; o <<= 1) lpair += __shfl_xor(lpair, o, 64);
  if (lane == 0) wred[w] = lpair;
  __syncthreads();
  if (tid == 0)
    atomicAdd(&acc[0], (double)((wred[0] + wred[1]) + (wred[2] + wred[3])));

  // write loc_pre (non-atomic) + g_score partials
  for (int idx = tid; idx < 16 * 128; idx += 256) {
    const int r = idx >> 7;
    const int c4 = (idx & 127) * 4;
    float4 v = *(const float4*)&loc_acc[r][c4];
    *(float4*)&loc_pre[((size_t)(b * Ln + i0 + r)) * Ln + c4] = v;
  }
  {
    const int j0 = tid, j1 = tid + 256;
    float g0 = 0.0f, g1 = 0.0f;
    for (int r = 0; r < 16; ++r) {
      g0 += loc_acc[r][j0];
      g1 += loc_acc[r][j1];
    }
    atomicAdd(&g_score[b * Ln + j0], g0);
    atomicAdd(&g_score[b * Ln + j1], g1);
  }
}

// ---------------------------------------------------------------------------
// Top-k helpers: iterative argmax with tie -> lowest index (jax.lax.top_k).
// ---------------------------------------------------------------------------
__global__ void topk_g_kernel(const float* __restrict__ g_score, int* __restrict__ g_top) {
  int b = blockIdx.x, tid = threadIdx.x;
  __shared__ float vals[Ln];
  __shared__ float bv[256];
  __shared__ int bi[256];
  vals[tid] = g_score[b * Ln + tid];
  vals[tid + 256] = g_score[b * Ln + tid + 256];
  __syncthreads();
  for (int r = 0; r < K1n; ++r) {
    float v0 = vals[tid], v1 = vals[tid + 256];
    float v; int idx;
    if (v1 > v0) { v = v1; idx = tid + 256; } else { v = v0; idx = tid; }
    bv[tid] = v; bi[tid] = idx;
    __syncthreads();
    for (int s = 128; s > 0; s >>= 1) {
      if (tid < s) {
        float ov = bv[tid + s]; int oi = bi[tid + s];
        if (ov > bv[tid] || (ov == bv[tid] && oi < bi[tid])) { bv[tid] = ov; bi[tid] = oi; }
      }
      __syncthreads();
    }
    if (tid == 0) { g_top[b * K1n + r] = bi[0]; vals[bi[0]] = -3.0e38f; }
    __syncthreads();
  }
}

__global__ void topk_l_kernel(const float* __restrict__ loc_pre,
                              const int* __restrict__ g_top, int* __restrict__ l_top) {
  int blk = blockIdx.x, tid = threadIdx.x;
  int b = blk / K1n, i1 = blk % K1n;
  int g = g_top[b * K1n + i1];
  __shared__ float vals[Ln];
  __shared__ float bv[256];
  __shared__ int bi[256];
  size_t rb = ((size_t)(b * Ln + g)) * Ln;
  vals[tid] = loc_pre[rb + tid];
  vals[tid + 256] = loc_pre[rb + tid + 256];
  __syncthreads();
  if (tid == 0) vals[g] = 0.0f;   // (1 - eye) zeroing of diagonal
  __syncthreads();
  for (int r = 0; r < K2n; ++r) {
    float v0 = vals[tid], v1 = vals[tid + 256];
    float v; int idx;
    if (v1 > v0) { v = v1; idx = tid + 256; } else { v = v0; idx = tid; }
    bv[tid] = v; bi[tid] = idx;
    __syncthreads();
    for (int s = 128; s > 0; s >>= 1) {
      if (tid < s) {
        float ov = bv[tid + s]; int oi = bi[tid + s];
        if (ov > bv[tid] || (ov == bv[tid] && oi < bi[tid])) { bv[tid] = ov; bi[tid] = oi; }
      }
      __syncthreads();
    }
    if (tid == 0) { l_top[(b * K1n + i1) * K2n + r] = bi[0]; vals[bi[0]] = -3.0e38f; }
    __syncthreads();
  }
}

// ---------------------------------------------------------------------------
// Triplet loss. One block per (b, i1). fp32 throughout.
// ---------------------------------------------------------------------------
__global__ __launch_bounds__(256, 1) void triplet_kernel(
    const float* __restrict__ s_rep, const float* __restrict__ t_rep,
    const float* __restrict__ mask, const int* __restrict__ g_top,
    const int* __restrict__ l_top, double* __restrict__ acc) {
  int blk = blockIdx.x, tid = threadIdx.x;
  int b = blk / K1n, i1 = blk % K1n;
  int wid = tid >> 6, lane = tid & 63;
  __shared__ float NS[K2n][Dn];
  __shared__ float NT[K2n][Dn];
  __shared__ int lidx[K2n];
  __shared__ float fl2[K2n];
  __shared__ float sred[4], cred[4];

  int g = g_top[b * K1n + i1];
  if (tid < K2n) {
    int li = l_top[(b * K1n + i1) * K2n + tid];
    lidx[tid] = li;
    fl2[tid] = (mask[b * Ln + g] + mask[b * Ln + li] == 2.0f) ? 1.0f : 0.0f;
  }
  __syncthreads();

  const float* pgs = s_rep + ((size_t)(b * Ln + g)) * Dn;
  const float* pgt = t_rep + ((size_t)(b * Ln + g)) * Dn;
  for (int j = wid; j < K2n; j += 4) {
    const float* pls = s_rep + ((size_t)(b * Ln + lidx[j])) * Dn;
    const float* plt = t_rep + ((size_t)(b * Ln + lidx[j])) * Dn;
    float4 ds[3], dt[3];
    float ssq = 0.0f, tsq = 0.0f;
    #pragma unroll
    for (int q = 0; q < 3; ++q) {
      int c = lane * 4 + q * 256;
      float4 a = *(const float4*)&pgs[c];
      float4 x = *(const float4*)&pls[c];
      ds[q] = make_float4(a.x - x.x, a.y - x.y, a.z - x.z, a.w - x.w);
      ssq += ds[q].x * ds[q].x + ds[q].y * ds[q].y + ds[q].z * ds[q].z + ds[q].w * ds[q].w;
      float4 c2 = *(const float4*)&pgt[c];
      float4 y = *(const float4*)&plt[c];
      dt[q] = make_float4(c2.x - y.x, c2.y - y.y, c2.z - y.z, c2.w - y.w);
      tsq += dt[q].x * dt[q].x + dt[q].y * dt[q].y + dt[q].z * dt[q].z + dt[q].w * dt[q].w;
    }
    #pragma unroll
    for (int o = 1; o < 64; o <<= 1) {
      ssq += __shfl_xor(ssq, o, 64);
      tsq += __shfl_xor(tsq, o, 64);
    }
    float sinv = 1.0f / fmaxf(sqrtf(ssq), 1e-12f);
    float tinv = 1.0f / fmaxf(sqrtf(tsq), 1e-12f);
    #pragma unroll
    for (int q = 0; q < 3; ++q) {
      int c = lane * 4 + q * 256;
      *(float4*)&NS[j][c] = make_float4(ds[q].x * sinv, ds[q].y * sinv, ds[q].z * sinv, ds[q].w * sinv);
      *(float4*)&NT[j][c] = make_float4(dt[q].x * tinv, dt[q].y * tinv, dt[q].z * tinv, dt[q].w * tinv);
    }
  }
  __syncthreads();

  float psum = 0.0f, pcnt = 0.0f;
  for (int p = wid; p < (K2n * (K2n - 1)) / 2; p += 4) {
    int j = 0, base = 0;
    while (p >= base + (K2n - 1 - j)) { base += K2n - 1 - j; ++j; }
    int k = j + 1 + (p - base);
    float dots = 0.0f, dott = 0.0f;
    #pragma unroll
    for (int q = 0; q < 3; ++q) {
      int c = lane * 4 + q * 256;
      float4 xs = *(const float4*)&NS[j][c];
      float4 ys = *(const float4*)&NS[k][c];
      dots += xs.x * ys.x + xs.y * ys.y + xs.z * ys.z + xs.w * ys.w;
      float4 xt = *(const float4*)&NT[j][c];
      float4 yt = *(const float4*)&NT[k][c];
      dott += xt.x * yt.x + xt.y * yt.y + xt.z * yt.z + xt.w * yt.w;
    }
    #pragma unroll
    for (int o = 1; o < 64; o <<= 1) {
      dots += __shfl_xor(dots, o, 64);
      dott += __shfl_xor(dott, o, 64);
    }
    if (lane == 0) {
      float am = fl2[j] * fl2[k];
      bool smv = (am != 0.0f) && (dots != 0.0f);
      bool tmv = (am != 0.0f) && (dott != 0.0f);
      float sv = smv ? dots : 0.0f;
      float tv = tmv ? dott : 0.0f;
      float d = sv - tv;
      float ad = fabsf(d);
      float sl1 = (ad < 1.0f) ? 0.5f * d * d : (ad - 0.5f);
      psum += 2.0f * sl1;                 // symmetric (j,k)/(k,j)
      pcnt += smv ? 2.0f : 0.0f;
    }
  }
  if (lane == 0) { sred[wid] = psum; cred[wid] = pcnt; }
  __syncthreads();
  if (tid == 0) {
    atomicAdd(&acc[1], (double)(sred[0] + sred[1] + sred[2] + sred[3]));
    atomicAdd(&acc[2], (double)(cred[0] + cred[1] + cred[2] + cred[3]));
  }
}

// ---------------------------------------------------------------------------
// Finalize: sum(mext) = sum_b (sum_i m)^2; combine losses.
// ---------------------------------------------------------------------------
__global__ void finalize_kernel(const float* __restrict__ mask,
                                const double* __restrict__ acc, float* __restrict__ out) {
  int tid = threadIdx.x;
  __shared__ float red[4];
  double sm = 0.0;
  for (int b = 0; b < Bn; ++b) {
    float p = 0.0f;
    for (int i = tid; i < Ln; i += 256) p += mask[b * Ln + i];
    #pragma unroll
    for (int o = 1; o < 64; o <<= 1) p += __shfl_xor(p, o, 64);
    __syncthreads();
    if ((tid & 63) == 0) red[tid >> 6] = p;
    __syncthreads();
    if (tid == 0) {
      float rs = red[0] + red[1] + red[2] + red[3];
      sm += (double)rs * (double)rs;
    }
  }
  __syncthreads();
  if (tid == 0) {
    double lp = acc[0] / ((double)NHn * sm);
    double lt = acc[1] / acc[2];
    out[0] = (float)(lp + lt);
  }
}

// ---------------------------------------------------------------------------
extern "C" void kernel_launch(void* const* d_in, const int* in_sizes, int n_in,
                              void* d_out, int out_size, void* d_ws, size_t ws_size,
                              hipStream_t stream) {
  const float* s_rep = (const float*)d_in[0];
  const float* t_rep = (const float*)d_in[1];
  const float* mask  = (const float*)d_in[2];
  float* out = (float*)d_out;

  char* w = (char*)d_ws;
  double* acc     = (double*)(w + WS_ACC);
  float* g_score  = (float*)(w + WS_GSCORE);
  float* loc_pre  = (float*)(w + WS_LOC);
  int* g_top      = (int*)(w + WS_GTOP);
  int* l_top      = (int*)(w + WS_LTOP);
  unsigned short* sbf = (unsigned short*)(w + WS_SBF);
  unsigned short* tbf = (unsigned short*)(w + WS_TBF);

  hipMemsetAsync(d_ws, 0, WS_ZERO_BYTES, stream);

  prep_bf16_kernel<<<Bn * Ln * Dn / 4 / 256, 256, 0, stream>>>(s_rep, t_rep, sbf, tbf);
  pair2_kernel<<<Bn * (Ln / 16), 256, 0, stream>>>(sbf, tbf, mask, loc_pre, g_score, acc);
  topk_g_kernel<<<Bn, 256, 0, stream>>>(g_score, g_top);
  topk_l_kernel<<<Bn * K1n, 256, 0, stream>>>(loc_pre, g_top, l_top);
  triplet_kernel<<<Bn * K1n, 256, 0, stream>>>(s_rep, t_rep, mask, g_top, l_top, acc);
  finalize_kernel<<<1, 256, 0, stream>>>(mask, acc, out);
}